// Round 6
// baseline (242.209 us; speedup 1.0000x reference)
//
#include <hip/hip_runtime.h>
#include <hip/hip_bf16.h>
#include <stdint.h>

// Problem constants (B=2, NV=25000, C=32, NR=3, ND=16, F=64)
#define NVERT 25000      // vertices per batch
#define NPAIR 25000      // total vertex-pairs (B*NV/2)
#define NGRP  12500      // pair-groups of 2 pairs (4 vertices) per wave-iter

typedef __bf16  bf16x8 __attribute__((ext_vector_type(8)));
typedef float   f32x16 __attribute__((ext_vector_type(16)));

#define NCHUNK 98                       // 96 conv chunks (r,ch,j) + 2 center chunks
#define BPACK_HALF_USHORT (NCHUNK*512)  // ushorts per f-half fragment pack
#define LDS_B   (NCHUNK*1024)           // 100352 B of B-fragments in LDS
#define ROWB    80                      // patch row stride (20 dw -> bank stride 20==4 mod 32; b128 balanced)
#define VSTRIDE (49*ROWB)               // per-vertex patch (48 rows + 1 center row) = 3920
#define WSTRIDE (4*VSTRIDE)             // per wave: 4 vertices (2 pairs) = 15680
#define LDS_TOT (LDS_B + 4*WSTRIDE)     // 163072 <= 163840

__device__ __forceinline__ uint2 pack4(float4 v) {
  union { __hip_bfloat162 h; unsigned u; } a, b;
  a.h = __float22bfloat162_rn(float2{v.x, v.y});
  b.h = __float22bfloat162_rn(float2{v.z, v.w});
  return uint2{a.u, b.u};
}

__device__ __forceinline__ unsigned short f2bf(float f) {
  unsigned int u = __float_as_uint(f);
  u += 0x7FFFu + ((u >> 16) & 1u);   // round-to-nearest-even
  return (unsigned short)(u >> 16);
}

// Pack kernel (3,16,32,64) + center_kernel (32,64) into MFMA B-fragment order, bf16.
// Layout: bpack[fh(2)][kc(98)][lane(64)][i(8)] ushort.
// kc = (r*2+ch)*16 + j for conv; kc = 96+ch for center. B[k][n]: n=lane&31, k=8*(lane>>5)+i, c=ch*16+k.
__global__ __launch_bounds__(256) void prepack_kernel(
    const float* __restrict__ kern, const float* __restrict__ ckern,
    unsigned short* __restrict__ bpack)
{
  int tid = blockIdx.x*256 + threadIdx.x;
  if (tid >= 2*BPACK_HALF_USHORT) return;
  int fh  = tid / BPACK_HALF_USHORT;
  int rem = tid - fh*BPACK_HALF_USHORT;
  int kc  = rem >> 9;
  int e   = rem & 511;
  int l   = e >> 3, i = e & 7;
  int f   = fh*32 + (l & 31);
  int kk  = ((l >> 5) << 3) + i;
  float v;
  if (kc < 96) {
    int r = kc >> 5, ch = (kc >> 4) & 1, j = kc & 15;
    int c = ch*16 + kk;
    v = kern[((r*16 + j)*32 + c)*64 + f];
  } else {
    int c = (kc - 96)*16 + kk;
    v = ckern[c*64 + f];
  }
  bpack[tid] = f2bf(v);
}

// Flattened chunk step s = rr*16 + j (rr = s>>4, j = s&15).
// A-fragment for (rr,j): LDS row (d+j)&15 of region rr — read directly, no DPP rotation.
// Triple-buffered: PREF(s) writes buf s%3, consumed by STEP(s) two steps later, so
// ds_read writes never collide with registers of in-flight MFMAs (1 full step of separation).
#define PREF(s)  do {                                                                   \
    const int buf_ = (s) % 3;                                                           \
    const char* va_ = abase + row[(s) & 15] + ((s) >> 4) * 1280;                        \
    A00[buf_] = *(const bf16x8*)(va_);                                                  \
    A01[buf_] = *(const bf16x8*)(va_ + 32);                                             \
    A10[buf_] = *(const bf16x8*)(va_ + 2*VSTRIDE);                                      \
    A11[buf_] = *(const bf16x8*)(va_ + 2*VSTRIDE + 32);                                 \
    B0[buf_]  = *(const bf16x8*)(bbase + (size_t)((((s)>>4)*2 + 0)*16 + ((s)&15))*1024);\
    B1[buf_]  = *(const bf16x8*)(bbase + (size_t)((((s)>>4)*2 + 1)*16 + ((s)&15))*1024);\
  } while (0)

#define STEP(s)  do {                                                                   \
    const int buf_ = (s) % 3;                                                           \
    acc00 = __builtin_amdgcn_mfma_f32_32x32x16_bf16(A00[buf_], B0[buf_], acc00, 0,0,0); \
    acc10 = __builtin_amdgcn_mfma_f32_32x32x16_bf16(A10[buf_], B0[buf_], acc10, 0,0,0); \
    acc01 = __builtin_amdgcn_mfma_f32_32x32x16_bf16(A01[buf_], B1[buf_], acc01, 0,0,0); \
    acc11 = __builtin_amdgcn_mfma_f32_32x32x16_bf16(A11[buf_], B1[buf_], acc11, 0,0,0); \
  } while (0)

__global__ __launch_bounds__(256, 1) void conv_kernel(
    const float* __restrict__ y,
    const int*   __restrict__ em,     // exp_map int pairs (b,v), flat (u*48 + r*16+dd)
    const float* __restrict__ bias,
    const unsigned short* __restrict__ bpack,
    float* __restrict__ out)
{
  extern __shared__ __align__(16) char smem[];
  const int fh  = blockIdx.x & 1;     // which 32-wide f half
  const int bl  = blockIdx.x >> 1;    // 0..127
  const int tid = threadIdx.x;
  const int w   = tid >> 6;           // wave 0..3
  const int l   = tid & 63;

  // ---- stage this f-half's B fragments into LDS (once per block) ----
  {
    const uint4* src = (const uint4*)(bpack + (size_t)fh * BPACK_HALF_USHORT);
    uint4* dst = (uint4*)smem;
    for (int idx = tid; idx < LDS_B/16; idx += 256) dst[idx] = src[idx];
  }
  __syncthreads();
  // No barriers after this; per-wave DS ordering protects the private patch buffer.

  char* pbase = smem + LDS_B + w * WSTRIDE;
  const char* bbase = smem + (size_t)l * 16;    // canonical fragment read: 0 conflicts (R3 PMC)
  const float biasv = bias[fh*32 + (l & 31)];
  const int gw = bl*4 + w;            // global wave id within f-half, 0..511
  const int q  = (l >> 4) & 1;        // A-operand: which vertex of the pair (m>>4)
  const int d  = l & 15;              // A-operand: direction (m&15)
  const int hi = l >> 5;              // A/B operand: k-half selector
  const char* abase = pbase + q*VSTRIDE + hi*16;    // + row*80 + rr*1280 (+32 per ch, +2*VSTRIDE pair 1)
  const int2* em2 = (const int2*)em;
  // staging lane roles: row-slot = l>>3 (8 rows/step), c-quarter = l&7
  const int rsl = l >> 3, cp = l & 7;

  // per-lane rotated row offsets: row[js] = ((d+js)&15)*80  (CSE'd across the 3 r-regions)
  int row[16];
#pragma unroll
  for (int js = 0; js < 16; ++js) row[js] = ((d + js) & 15) * ROWB;

  int g = gw;
  bool valid = (g < NGRP);

  // ---- prologue: stage group g fully (latency exposed once) ----
  if (valid) {
    int2 e0[24];
#pragma unroll
    for (int it = 0; it < 24; ++it)
      e0[it] = em2[(g*4 + (it & 3))*48 + (it >> 2)*8 + rsl];
    float4 yv0[25];
#pragma unroll
    for (int it = 0; it < 24; ++it)
      yv0[it] = *(const float4*)(y + ((size_t)e0[it].x*NVERT + (size_t)e0[it].y)*32 + cp*4);
    yv0[24] = *(const float4*)(y + (size_t)(g*4 + (rsl & 3))*32 + cp*4);
#pragma unroll
    for (int it = 0; it < 24; ++it)
      *(uint2*)(pbase + (it & 3)*VSTRIDE + ((it >> 2)*8 + rsl)*ROWB + cp*8) = pack4(yv0[it]);
    if (l < 32)
      *(uint2*)(pbase + rsl*VSTRIDE + 48*ROWB + cp*8) = pack4(yv0[24]);
  }

  for (int t = 0; t < 25; ++t) {
    if (!valid) break;
    const int gn = g + 512;
    const bool vnext = (gn < NGRP);

    // ---- Phase A: issue next group's em loads (latency hidden by r=0 compute) ----
    int2 e[24];
    if (vnext) {
#pragma unroll
      for (int it = 0; it < 24; ++it)
        e[it] = em2[(gn*4 + (it & 3))*48 + (it >> 2)*8 + rsl];
    }

    f32x16 acc00, acc01, acc10, acc11;
#pragma unroll
    for (int k = 0; k < 16; ++k) {
      acc00[k] = 0.f; acc01[k] = 0.f; acc10[k] = 0.f; acc11[k] = 0.f;
    }

    bf16x8 A00[3], A01[3], A10[3], A11[3], B0[3], B1[3];
    PREF(0); PREF(1);

    // ---- Phase B: r=0 steps (MFMA pipe covers em latency) ----
#pragma unroll
    for (int s = 0; s < 16; ++s) { PREF(s + 2); STEP(s); }

    // ---- Phase C: issue next group's y gathers (latency hidden by r=1,2) ----
    float4 yv[25];
    if (vnext) {
#pragma unroll
      for (int it = 0; it < 24; ++it)
        yv[it] = *(const float4*)(y + ((size_t)e[it].x*NVERT + (size_t)e[it].y)*32 + cp*4);
      yv[24] = *(const float4*)(y + (size_t)(gn*4 + (rsl & 3))*32 + cp*4);
    }

    // ---- Phase D: r=1, r=2 steps + center ----
#pragma unroll
    for (int s = 16; s < 48; ++s) { if (s + 2 < 48) PREF(s + 2); STEP(s); }
    {
      const bf16x8 bc0 = *(const bf16x8*)(bbase + (size_t)96*1024);
      const bf16x8 bc1 = *(const bf16x8*)(bbase + (size_t)97*1024);
      const char* c0 = abase + 48*ROWB;
      bf16x8 a00 = *(const bf16x8*)c0;
      bf16x8 a01 = *(const bf16x8*)(c0 + 32);
      bf16x8 a10 = *(const bf16x8*)(c0 + 2*VSTRIDE);
      bf16x8 a11 = *(const bf16x8*)(c0 + 2*VSTRIDE + 32);
      acc00 = __builtin_amdgcn_mfma_f32_32x32x16_bf16(a00, bc0, acc00, 0,0,0);
      acc10 = __builtin_amdgcn_mfma_f32_32x32x16_bf16(a10, bc0, acc10, 0,0,0);
      acc01 = __builtin_amdgcn_mfma_f32_32x32x16_bf16(a01, bc1, acc01, 0,0,0);
      acc11 = __builtin_amdgcn_mfma_f32_32x32x16_bf16(a11, bc1, acc11, 0,0,0);
    }

    // ---- Phase E: epilogue — sum c-halves, max over d, +bias, relu, store ----
    // C/D layout (m74/m101): n = lane&31, m = (reg&3)+8*(reg>>2)+4*(lane>>5).
    {
      float m0 = acc00[0] + acc01[0], m1 = acc00[8] + acc01[8];
#pragma unroll
      for (int k = 1; k < 8; ++k) {
        m0 = fmaxf(m0, acc00[k]   + acc01[k]);
        m1 = fmaxf(m1, acc00[8+k] + acc01[8+k]);
      }
      m0 = fmaxf(m0, __shfl_xor(m0, 32, 64));
      m1 = fmaxf(m1, __shfl_xor(m1, 32, 64));
      float v = (hi ? m1 : m0) + biasv;
      out[(size_t)(g*4 + hi)*64 + fh*32 + (l & 31)] = fmaxf(v, 0.f);
    }
    {
      float m0 = acc10[0] + acc11[0], m1 = acc10[8] + acc11[8];
#pragma unroll
      for (int k = 1; k < 8; ++k) {
        m0 = fmaxf(m0, acc10[k]   + acc11[k]);
        m1 = fmaxf(m1, acc10[8+k] + acc11[8+k]);
      }
      m0 = fmaxf(m0, __shfl_xor(m0, 32, 64));
      m1 = fmaxf(m1, __shfl_xor(m1, 32, 64));
      float v = (hi ? m1 : m0) + biasv;
      out[(size_t)(g*4 + 2 + hi)*64 + fh*32 + (l & 31)] = fmaxf(v, 0.f);
    }

    // ---- Phase F: pack + ds_write next group's patches (y latency now drained) ----
    if (vnext) {
#pragma unroll
      for (int it = 0; it < 24; ++it)
        *(uint2*)(pbase + (it & 3)*VSTRIDE + ((it >> 2)*8 + rsl)*ROWB + cp*8) = pack4(yv[it]);
      if (l < 32)
        *(uint2*)(pbase + rsl*VSTRIDE + 48*ROWB + cp*8) = pack4(yv[24]);
    }

    g = gn; valid = vnext;
  }
}

extern "C" void kernel_launch(void* const* d_in, const int* in_sizes, int n_in,
                              void* d_out, int out_size, void* d_ws, size_t ws_size,
                              hipStream_t stream) {
  const float* y     = (const float*)d_in[0];
  const int*   em    = (const int*)  d_in[1];
  const float* kern  = (const float*)d_in[2];
  const float* ckern = (const float*)d_in[3];
  const float* bias  = (const float*)d_in[4];
  float* out = (float*)d_out;
  unsigned short* bpack = (unsigned short*)d_ws;   // 200704 bytes used

  // opt in to >64KB dynamic LDS (host-side, graph-capture safe — verified rounds 1-5)
  hipFuncSetAttribute(reinterpret_cast<const void*>(conv_kernel),
                      hipFuncAttributeMaxDynamicSharedMemorySize, LDS_TOT);

  prepack_kernel<<<(2*BPACK_HALF_USHORT + 255)/256, 256, 0, stream>>>(kern, ckern, bpack);
  conv_kernel<<<256, 256, LDS_TOT, stream>>>(y, em, bias, bpack, out);
}

// Round 7
// 231.432 us; speedup vs baseline: 1.0466x; 1.0466x over previous
//
#include <hip/hip_runtime.h>
#include <hip/hip_bf16.h>
#include <stdint.h>

// Problem constants (B=2, NV=25000, C=32, NR=3, ND=16, F=64)
#define NVERT 25000      // vertices per batch
#define NPAIR 25000      // total vertex-pairs (B*NV/2)
#define NGRP  12500      // pair-groups of 2 pairs (4 vertices) per wave-iter

typedef __bf16  bf16x8 __attribute__((ext_vector_type(8)));
typedef float   f32x16 __attribute__((ext_vector_type(16)));

#define NCHUNK 98                       // 96 conv chunks (r,ch,j) + 2 center chunks
#define BPACK_HALF_USHORT (NCHUNK*512)  // ushorts per f-half fragment pack
#define LDS_B   (NCHUNK*1024)           // 100352 B of B-fragments in LDS
#define ROWB    80                      // patch row stride (32 bf16 + 16B pad)
#define VSTRIDE (49*ROWB)               // per-vertex patch (48 rows + 1 center row) = 3920
#define WSTRIDE (4*VSTRIDE)             // per wave: 4 vertices (2 pairs) = 15680
#define LDS_TOT (LDS_B + 4*WSTRIDE)     // 163072 <= 163840

__device__ __forceinline__ uint2 pack4(float4 v) {
  union { __hip_bfloat162 h; unsigned u; } a, b;
  a.h = __float22bfloat162_rn(float2{v.x, v.y});
  b.h = __float22bfloat162_rn(float2{v.z, v.w});
  return uint2{a.u, b.u};
}

__device__ __forceinline__ unsigned short f2bf(float f) {
  unsigned int u = __float_as_uint(f);
  u += 0x7FFFu + ((u >> 16) & 1u);   // round-to-nearest-even
  return (unsigned short)(u >> 16);
}

// lane-rotate within 16-lane rows (row_ror:15): dst[i] = src[(i+1)&15] — verified (R1+ pass)
__device__ __forceinline__ bf16x8 rot16(bf16x8 x) {
  union { bf16x8 v; int i[4]; } u;
  u.v = x;
#pragma unroll
  for (int k = 0; k < 4; ++k)
    u.i[k] = __builtin_amdgcn_update_dpp(0, u.i[k], 0x12F, 0xF, 0xF, true);
  return u.v;
}

// Pack kernel (3,16,32,64) + center_kernel (32,64) into MFMA B-fragment order, bf16.
// Layout: bpack[fh(2)][kc(98)][lane(64)][i(8)] ushort.
// kc = (r*2+ch)*16 + j for conv; kc = 96+ch for center. B[k][n]: n=lane&31, k=8*(lane>>5)+i, c=ch*16+k.
__global__ __launch_bounds__(256) void prepack_kernel(
    const float* __restrict__ kern, const float* __restrict__ ckern,
    unsigned short* __restrict__ bpack)
{
  int tid = blockIdx.x*256 + threadIdx.x;
  if (tid >= 2*BPACK_HALF_USHORT) return;
  int fh  = tid / BPACK_HALF_USHORT;
  int rem = tid - fh*BPACK_HALF_USHORT;
  int kc  = rem >> 9;
  int e   = rem & 511;
  int l   = e >> 3, i = e & 7;
  int f   = fh*32 + (l & 31);
  int kk  = ((l >> 5) << 3) + i;
  float v;
  if (kc < 96) {
    int r = kc >> 5, ch = (kc >> 4) & 1, j = kc & 15;
    int c = ch*16 + kk;
    v = kern[((r*16 + j)*32 + c)*64 + f];
  } else {
    int c = (kc - 96)*16 + kk;
    v = ckern[c*64 + f];
  }
  bpack[tid] = f2bf(v);
}

// One r-pass: A loaded fresh from LDS at j=0 then DPP-rotated through a 3-slot ring
// (rot writes slot (j+1)%3 while MFMA reads slot j%3 — write target last touched 2 steps
// (~300 cyc) earlier, so no WAR window against in-flight MFMAs and the allocator cannot
// coalesce the ring into one physical register). B: 3-slot ring, distance-2 LDS prefetch
// (no shift-copies). 4 independent accumulator chains.
#define PASS(rr)                                                                \
  {                                                                             \
    const char* ap = abase + (rr)*1280;                                         \
    bf16x8 A[3][4];                                                             \
    A[0][0] = *(const bf16x8*)(ap);                                             \
    A[0][1] = *(const bf16x8*)(ap + 32);                                        \
    A[0][2] = *(const bf16x8*)(ap + 2*VSTRIDE);                                 \
    A[0][3] = *(const bf16x8*)(ap + 2*VSTRIDE + 32);                            \
    const char* bp0 = bbase + (size_t)(((rr)*2 + 0)*16) * 1024;                 \
    const char* bp1 = bbase + (size_t)(((rr)*2 + 1)*16) * 1024;                 \
    bf16x8 Bb[3][2];                                                            \
    Bb[0][0] = *(const bf16x8*)bp0;                                             \
    Bb[0][1] = *(const bf16x8*)bp1;                                             \
    Bb[1][0] = *(const bf16x8*)(bp0 + 1024);                                    \
    Bb[1][1] = *(const bf16x8*)(bp1 + 1024);                                    \
    _Pragma("unroll")                                                           \
    for (int j = 0; j < 16; ++j) {                                              \
      const int cs = j % 3, ps = (j + 2) % 3, ns = (j + 1) % 3;                 \
      if (j < 14) {                                                             \
        Bb[ps][0] = *(const bf16x8*)(bp0 + (size_t)(j+2)*1024);                 \
        Bb[ps][1] = *(const bf16x8*)(bp1 + (size_t)(j+2)*1024);                 \
      }                                                                         \
      acc00 = __builtin_amdgcn_mfma_f32_32x32x16_bf16(A[cs][0], Bb[cs][0], acc00, 0,0,0); \
      acc10 = __builtin_amdgcn_mfma_f32_32x32x16_bf16(A[cs][2], Bb[cs][0], acc10, 0,0,0); \
      acc01 = __builtin_amdgcn_mfma_f32_32x32x16_bf16(A[cs][1], Bb[cs][1], acc01, 0,0,0); \
      acc11 = __builtin_amdgcn_mfma_f32_32x32x16_bf16(A[cs][3], Bb[cs][1], acc11, 0,0,0); \
      if (j < 15) {                                                             \
        A[ns][0] = rot16(A[cs][0]);                                             \
        A[ns][1] = rot16(A[cs][1]);                                             \
        A[ns][2] = rot16(A[cs][2]);                                             \
        A[ns][3] = rot16(A[cs][3]);                                             \
      }                                                                         \
    }                                                                           \
  }

__global__ __launch_bounds__(256, 1) void conv_kernel(
    const float* __restrict__ y,
    const int*   __restrict__ em,     // exp_map int pairs (b,v), flat (u*48 + r*16+dd)
    const float* __restrict__ bias,
    const unsigned short* __restrict__ bpack,
    float* __restrict__ out)
{
  extern __shared__ __align__(16) char smem[];
  const int fh  = blockIdx.x & 1;     // which 32-wide f half
  const int bl  = blockIdx.x >> 1;    // 0..127
  const int tid = threadIdx.x;
  const int w   = tid >> 6;           // wave 0..3
  const int l   = tid & 63;

  // ---- stage this f-half's B fragments into LDS (once per block) ----
  {
    const uint4* src = (const uint4*)(bpack + (size_t)fh * BPACK_HALF_USHORT);
    uint4* dst = (uint4*)smem;
    for (int idx = tid; idx < LDS_B/16; idx += 256) dst[idx] = src[idx];
  }
  __syncthreads();
  // No barriers after this; per-wave DS ordering protects the private patch buffer.

  char* pbase = smem + LDS_B + w * WSTRIDE;
  const char* bbase = smem + (size_t)l * 16;    // canonical fragment read: 0 conflicts (R3 PMC)
  const float biasv = bias[fh*32 + (l & 31)];
  const int gw = bl*4 + w;            // global wave id within f-half, 0..511
  const int q  = (l >> 4) & 1;        // A-operand: which vertex of the pair (m>>4)
  const int d  = l & 15;              // A-operand: direction (m&15)
  const int hi = l >> 5;              // A/B operand: k-half selector
  const char* abase = pbase + q*VSTRIDE + d*ROWB + hi*16;  // j=0 fragment; +rr*1280 per region
  const int2* em2 = (const int2*)em;
  // staging lane roles: row-slot = l>>3 (8 rows/step), c-quarter = l&7
  const int rsl = l >> 3, cp = l & 7;

  int g = gw;
  bool valid = (g < NGRP);

  // ---- prologue: stage group g fully (latency exposed once) ----
  if (valid) {
    int2 e0[24];
#pragma unroll
    for (int it = 0; it < 24; ++it)
      e0[it] = em2[(g*4 + (it & 3))*48 + (it >> 2)*8 + rsl];
    float4 yv0[25];
#pragma unroll
    for (int it = 0; it < 24; ++it)
      yv0[it] = *(const float4*)(y + ((size_t)e0[it].x*NVERT + (size_t)e0[it].y)*32 + cp*4);
    yv0[24] = *(const float4*)(y + (size_t)(g*4 + (rsl & 3))*32 + cp*4);
#pragma unroll
    for (int it = 0; it < 24; ++it)
      *(uint2*)(pbase + (it & 3)*VSTRIDE + ((it >> 2)*8 + rsl)*ROWB + cp*8) = pack4(yv0[it]);
    if (l < 32)
      *(uint2*)(pbase + rsl*VSTRIDE + 48*ROWB + cp*8) = pack4(yv0[24]);
  }

  for (int t = 0; t < 25; ++t) {
    if (!valid) break;
    const int gn = g + 512;
    const bool vnext = (gn < NGRP);

    // ---- Phase A: issue next group's em loads (latency hidden by r=0 compute) ----
    int2 e[24];
    if (vnext) {
#pragma unroll
      for (int it = 0; it < 24; ++it)
        e[it] = em2[(gn*4 + (it & 3))*48 + (it >> 2)*8 + rsl];
    }

    f32x16 acc00, acc01, acc10, acc11;
#pragma unroll
    for (int k = 0; k < 16; ++k) {
      acc00[k] = 0.f; acc01[k] = 0.f; acc10[k] = 0.f; acc11[k] = 0.f;
    }

    // ---- Phase B: r=0 (MFMA pipe covers em latency) ----
    PASS(0)

    // ---- Phase C: issue next group's y gathers (latency hidden by r=1,2) ----
    float4 yv[25];
    if (vnext) {
#pragma unroll
      for (int it = 0; it < 24; ++it)
        yv[it] = *(const float4*)(y + ((size_t)e[it].x*NVERT + (size_t)e[it].y)*32 + cp*4);
      yv[24] = *(const float4*)(y + (size_t)(gn*4 + (rsl & 3))*32 + cp*4);
    }

    // ---- Phase D: r=1, r=2, center ----
    PASS(1)
    PASS(2)
    {
      const bf16x8 bc0 = *(const bf16x8*)(bbase + (size_t)96*1024);
      const bf16x8 bc1 = *(const bf16x8*)(bbase + (size_t)97*1024);
      const char* c0 = pbase + q*VSTRIDE + 48*ROWB + hi*16;
      bf16x8 a00 = *(const bf16x8*)c0;
      bf16x8 a01 = *(const bf16x8*)(c0 + 32);
      bf16x8 a10 = *(const bf16x8*)(c0 + 2*VSTRIDE);
      bf16x8 a11 = *(const bf16x8*)(c0 + 2*VSTRIDE + 32);
      acc00 = __builtin_amdgcn_mfma_f32_32x32x16_bf16(a00, bc0, acc00, 0,0,0);
      acc10 = __builtin_amdgcn_mfma_f32_32x32x16_bf16(a10, bc0, acc10, 0,0,0);
      acc01 = __builtin_amdgcn_mfma_f32_32x32x16_bf16(a01, bc1, acc01, 0,0,0);
      acc11 = __builtin_amdgcn_mfma_f32_32x32x16_bf16(a11, bc1, acc11, 0,0,0);
    }

    // ---- Phase E: epilogue — sum c-halves, max over d, +bias, relu, store ----
    // C/D layout (m74/m101): n = lane&31, m = (reg&3)+8*(reg>>2)+4*(lane>>5).
    {
      float m0 = acc00[0] + acc01[0], m1 = acc00[8] + acc01[8];
#pragma unroll
      for (int k = 1; k < 8; ++k) {
        m0 = fmaxf(m0, acc00[k]   + acc01[k]);
        m1 = fmaxf(m1, acc00[8+k] + acc01[8+k]);
      }
      m0 = fmaxf(m0, __shfl_xor(m0, 32, 64));
      m1 = fmaxf(m1, __shfl_xor(m1, 32, 64));
      float v = (hi ? m1 : m0) + biasv;
      out[(size_t)(g*4 + hi)*64 + fh*32 + (l & 31)] = fmaxf(v, 0.f);
    }
    {
      float m0 = acc10[0] + acc11[0], m1 = acc10[8] + acc11[8];
#pragma unroll
      for (int k = 1; k < 8; ++k) {
        m0 = fmaxf(m0, acc10[k]   + acc11[k]);
        m1 = fmaxf(m1, acc10[8+k] + acc11[8+k]);
      }
      m0 = fmaxf(m0, __shfl_xor(m0, 32, 64));
      m1 = fmaxf(m1, __shfl_xor(m1, 32, 64));
      float v = (hi ? m1 : m0) + biasv;
      out[(size_t)(g*4 + 2 + hi)*64 + fh*32 + (l & 31)] = fmaxf(v, 0.f);
    }

    // ---- Phase F: pack + ds_write next group's patches (y latency now drained) ----
    if (vnext) {
#pragma unroll
      for (int it = 0; it < 24; ++it)
        *(uint2*)(pbase + (it & 3)*VSTRIDE + ((it >> 2)*8 + rsl)*ROWB + cp*8) = pack4(yv[it]);
      if (l < 32)
        *(uint2*)(pbase + rsl*VSTRIDE + 48*ROWB + cp*8) = pack4(yv[24]);
    }

    g = gn; valid = vnext;
  }
}

extern "C" void kernel_launch(void* const* d_in, const int* in_sizes, int n_in,
                              void* d_out, int out_size, void* d_ws, size_t ws_size,
                              hipStream_t stream) {
  const float* y     = (const float*)d_in[0];
  const int*   em    = (const int*)  d_in[1];
  const float* kern  = (const float*)d_in[2];
  const float* ckern = (const float*)d_in[3];
  const float* bias  = (const float*)d_in[4];
  float* out = (float*)d_out;
  unsigned short* bpack = (unsigned short*)d_ws;   // 200704 bytes used

  // opt in to >64KB dynamic LDS (host-side, graph-capture safe — verified rounds 1-6)
  hipFuncSetAttribute(reinterpret_cast<const void*>(conv_kernel),
                      hipFuncAttributeMaxDynamicSharedMemorySize, LDS_TOT);

  prepack_kernel<<<(2*BPACK_HALF_USHORT + 255)/256, 256, 0, stream>>>(kern, ckern, bpack);
  conv_kernel<<<256, 256, LDS_TOT, stream>>>(y, em, bias, bpack, out);
}

// Round 8
// 222.803 us; speedup vs baseline: 1.0871x; 1.0387x over previous
//
#include <hip/hip_runtime.h>
#include <hip/hip_bf16.h>
#include <stdint.h>

// Problem constants (B=2, NV=25000, C=32, NR=3, ND=16, F=64)
#define NVERT 25000      // vertices per batch
#define NPAIR 25000      // total vertex-pairs (B*NV/2)
#define NGRP  12500      // pair-groups of 2 pairs (4 vertices) per team-iter

typedef __bf16  bf16x8 __attribute__((ext_vector_type(8)));
typedef float   f32x16 __attribute__((ext_vector_type(16)));

#define NCHUNK 98                       // 96 conv chunks (r,ch,j) + 2 center chunks
#define BPACK_HALF_USHORT (NCHUNK*512)  // ushorts per f-half fragment pack
#define LDS_B   (NCHUNK*1024)           // 100352 B of B-fragments in LDS
#define ROWB    80                      // patch row stride (32 bf16 + 16B pad)
#define VSTRIDE (49*ROWB)               // per-vertex patch (48 rows + 1 center row) = 3920
#define WSTRIDE (4*VSTRIDE)             // per team: 4 vertices (2 pairs) = 15680
#define LDS_TOT (LDS_B + 4*WSTRIDE)     // 163072 <= 163840; one 512-thr block/CU = 2 waves/SIMD

__device__ __forceinline__ uint2 pack4(float4 v) {
  union { __hip_bfloat162 h; unsigned u; } a, b;
  a.h = __float22bfloat162_rn(float2{v.x, v.y});
  b.h = __float22bfloat162_rn(float2{v.z, v.w});
  return uint2{a.u, b.u};
}

__device__ __forceinline__ unsigned pk2(float a, float b) {
  union { __hip_bfloat162 h; unsigned u; } t;
  t.h = __float22bfloat162_rn(float2{a, b});
  return t.u;          // low16 = a, high16 = b
}

__device__ __forceinline__ unsigned short f2bf(float f) {
  unsigned int u = __float_as_uint(f);
  u += 0x7FFFu + ((u >> 16) & 1u);   // round-to-nearest-even
  return (unsigned short)(u >> 16);
}

// lane-rotate within 16-lane rows (row_ror:15): dst[i] = src[(i+1)&15] — verified (R1+ pass)
__device__ __forceinline__ bf16x8 rot16(bf16x8 x) {
  union { bf16x8 v; int i[4]; } u;
  u.v = x;
#pragma unroll
  for (int k = 0; k < 4; ++k)
    u.i[k] = __builtin_amdgcn_update_dpp(0, u.i[k], 0x12F, 0xF, 0xF, true);
  return u.v;
}

// Pack kernel (3,16,32,64) + center_kernel (32,64) into MFMA B-fragment order, bf16.
// Layout: bpack[fh(2)][kc(98)][lane(64)][i(8)] ushort.
// kc = (r*2+ch)*16 + j for conv; kc = 96+ch for center. B[k][n]: n=lane&31, k=8*(lane>>5)+i, c=ch*16+k.
__global__ __launch_bounds__(256) void prepack_kernel(
    const float* __restrict__ kern, const float* __restrict__ ckern,
    unsigned short* __restrict__ bpack)
{
  int tid = blockIdx.x*256 + threadIdx.x;
  if (tid >= 2*BPACK_HALF_USHORT) return;
  int fh  = tid / BPACK_HALF_USHORT;
  int rem = tid - fh*BPACK_HALF_USHORT;
  int kc  = rem >> 9;
  int e   = rem & 511;
  int l   = e >> 3, i = e & 7;
  int f   = fh*32 + (l & 31);
  int kk  = ((l >> 5) << 3) + i;
  float v;
  if (kc < 96) {
    int r = kc >> 5, ch = (kc >> 4) & 1, j = kc & 15;
    int c = ch*16 + kk;
    v = kern[((r*16 + j)*32 + c)*64 + f];
  } else {
    int c = (kc - 96)*16 + kk;
    v = ckern[c*64 + f];
  }
  bpack[tid] = f2bf(v);
}

// One r-pass for THIS wave's c-half: 1 B-read/step feeds both pairs' MFMAs.
// A rotated in-register (DPP); B 2-deep reg-prefetched.
#define PASS(rr)                                                               \
  {                                                                            \
    const char* ap = pbase + q*VSTRIDE + ((rr)*16 + d)*ROWB + choff + hi*16;   \
    bf16x8 a0 = *(const bf16x8*)ap;                                            \
    bf16x8 a1 = *(const bf16x8*)(ap + 2*VSTRIDE);                              \
    const char* bp = bbase + (size_t)(((rr)*2 + ch)*16) * 1024;                \
    bf16x8 b0 = *(const bf16x8*)bp;                                            \
    bf16x8 b1 = *(const bf16x8*)(bp + 1024);                                   \
    _Pragma("unroll")                                                          \
    for (int j = 0; j < 16; ++j) {                                             \
      const bf16x8 b = b0;                                                     \
      b0 = b1;                                                                 \
      if (j < 14) b1 = *(const bf16x8*)(bp + (size_t)(j+2)*1024);              \
      acc0 = __builtin_amdgcn_mfma_f32_32x32x16_bf16(a0, b, acc0, 0, 0, 0);    \
      acc1 = __builtin_amdgcn_mfma_f32_32x32x16_bf16(a1, b, acc1, 0, 0, 0);    \
      if (j < 15) { a0 = rot16(a0); a1 = rot16(a1); }                          \
    }                                                                          \
  }

__global__ __launch_bounds__(512, 2) void conv_kernel(
    const float* __restrict__ y,
    const int*   __restrict__ em,     // exp_map int pairs (b,v), flat (u*48 + r*16+dd)
    const float* __restrict__ bias,
    const unsigned short* __restrict__ bpack,
    float* __restrict__ out)
{
  extern __shared__ __align__(16) char smem[];
  const int fh  = blockIdx.x & 1;     // which 32-wide f half
  const int bl  = blockIdx.x >> 1;    // 0..127
  const int tid = threadIdx.x;
  const int w   = tid >> 6;           // wave 0..7
  const int tm  = w & 3;              // team 0..3 (patch region)
  const int ch  = w >> 2;             // role: c-half this wave computes
  const int l   = tid & 63;

  // ---- stage this f-half's B fragments into LDS (once per block) ----
  {
    const uint4* src = (const uint4*)(bpack + (size_t)fh * BPACK_HALF_USHORT);
    uint4* dst = (uint4*)smem;
    for (int idx = tid; idx < LDS_B/16; idx += 512) dst[idx] = src[idx];
  }
  // visibility ensured by B0 barrier at loop top (t=0)

  char* pbase = smem + LDS_B + tm * WSTRIDE;
  const char* bbase = smem + (size_t)l * 16;    // canonical fragment read: 0 conflicts (R3 PMC)
  const float biasv = bias[fh*32 + (l & 31)];
  const int gw = bl*4 + tm;           // team id within f-half, 0..511
  const int q  = (l >> 4) & 1;        // A-operand: which vertex of the pair (m>>4)
  const int d  = l & 15;              // A-operand: direction (m&15)
  const int hi = l >> 5;              // A/B operand: k-half selector
  const int choff = ch*32;            // byte offset of this wave's c-half within a row
  const int chv = ch*2;               // first vertex this role stages (role-split staging)
  const int2* em2 = (const int2*)em;
  const int rsl = l >> 3, cp = l & 7; // staging lane roles

  int g = gw;
  bool valid = (g < NGRP);

  // ---- prologue: stage this role's half of group g (vertices chv, chv+1) ----
  if (valid) {
    int2 e0[12];
#pragma unroll
    for (int it = 0; it < 12; ++it)
      e0[it] = em2[(g*4 + chv + (it & 1))*48 + (it >> 1)*8 + rsl];
    float4 yv0[12];
#pragma unroll
    for (int it = 0; it < 12; ++it)
      yv0[it] = *(const float4*)(y + ((size_t)e0[it].x*NVERT + (size_t)e0[it].y)*32 + cp*4);
    float4 yc0;
    if (l < 16) yc0 = *(const float4*)(y + (size_t)(g*4 + chv + rsl)*32 + cp*4);
#pragma unroll
    for (int it = 0; it < 12; ++it)
      *(uint2*)(pbase + (chv + (it & 1))*VSTRIDE + ((it >> 1)*8 + rsl)*ROWB + cp*8) = pack4(yv0[it]);
    if (l < 16)
      *(uint2*)(pbase + (chv + rsl)*VSTRIDE + 48*ROWB + cp*8) = pack4(yc0);
  }

  for (int t = 0; t < 25; ++t) {
    if (!valid) break;
    __syncthreads();   // B0: all staging (and t=0 B-pack copy) visible before reads

    const int gn = g + 512;
    const bool vnext = (gn < NGRP);

    // ---- Phase A: next group's em loads (latency hidden by r=0 compute) ----
    int2 e[12];
    if (vnext) {
#pragma unroll
      for (int it = 0; it < 12; ++it)
        e[it] = em2[(gn*4 + chv + (it & 1))*48 + (it >> 1)*8 + rsl];
    }

    f32x16 acc0, acc1;
#pragma unroll
    for (int k = 0; k < 16; ++k) { acc0[k] = 0.f; acc1[k] = 0.f; }

    // ---- Phase B: r=0 ----
    PASS(0)

    // ---- Phase C: next group's y gathers (latency hidden by r=1,2) ----
    float4 yv[12], yc;
    if (vnext) {
#pragma unroll
      for (int it = 0; it < 12; ++it)
        yv[it] = *(const float4*)(y + ((size_t)e[it].x*NVERT + (size_t)e[it].y)*32 + cp*4);
      if (l < 16) yc = *(const float4*)(y + (size_t)(gn*4 + chv + rsl)*32 + cp*4);
    }

    // ---- Phase D: r=1, r=2, center (this c-half only) ----
    PASS(1)
    PASS(2)
    {
      const bf16x8 bc = *(const bf16x8*)(bbase + (size_t)(96 + ch)*1024);
      const char* c0 = pbase + q*VSTRIDE + 48*ROWB + choff + hi*16;
      bf16x8 a0 = *(const bf16x8*)c0;
      bf16x8 a1 = *(const bf16x8*)(c0 + 2*VSTRIDE);
      acc0 = __builtin_amdgcn_mfma_f32_32x32x16_bf16(a0, bc, acc0, 0, 0, 0);
      acc1 = __builtin_amdgcn_mfma_f32_32x32x16_bf16(a1, bc, acc1, 0, 0, 0);
    }

    __syncthreads();   // B1: all patch A-reads of this group done

    // ---- Exchange: ch1 wave ships its partial accs (bf16-packed, 4KB) through
    //      the consumed patch region. Canonical layout: chunk*1024 + lane*16 (0 conflicts).
    if (ch) {
      uint4 s0 = {pk2(acc0[0],acc0[1]),  pk2(acc0[2],acc0[3]),
                  pk2(acc0[4],acc0[5]),  pk2(acc0[6],acc0[7])};
      uint4 s1 = {pk2(acc0[8],acc0[9]),  pk2(acc0[10],acc0[11]),
                  pk2(acc0[12],acc0[13]),pk2(acc0[14],acc0[15])};
      uint4 s2 = {pk2(acc1[0],acc1[1]),  pk2(acc1[2],acc1[3]),
                  pk2(acc1[4],acc1[5]),  pk2(acc1[6],acc1[7])};
      uint4 s3 = {pk2(acc1[8],acc1[9]),  pk2(acc1[10],acc1[11]),
                  pk2(acc1[12],acc1[13]),pk2(acc1[14],acc1[15])};
      *(uint4*)(pbase + 0*1024 + l*16) = s0;
      *(uint4*)(pbase + 1*1024 + l*16) = s1;
      *(uint4*)(pbase + 2*1024 + l*16) = s2;
      *(uint4*)(pbase + 3*1024 + l*16) = s3;
    }

    __syncthreads();   // B2: exchange visible

    if (!ch) {
      // ---- reduce + epilogue (ch0 wave): sum partner's c-half, max over d, +bias, relu ----
      // C/D layout (m74/m101): n = lane&31, m = (reg&3)+8*(reg>>2)+4*(lane>>5).
      uint4 x0 = *(const uint4*)(pbase + 0*1024 + l*16);
      uint4 x1 = *(const uint4*)(pbase + 1*1024 + l*16);
      uint4 x2 = *(const uint4*)(pbase + 2*1024 + l*16);
      uint4 x3 = *(const uint4*)(pbase + 3*1024 + l*16);
#pragma unroll
      for (int k = 0; k < 4; ++k) {
        unsigned u0 = (&x0.x)[k], u1 = (&x1.x)[k], u2 = (&x2.x)[k], u3 = (&x3.x)[k];
        acc0[2*k]   += __uint_as_float(u0 << 16);
        acc0[2*k+1] += __uint_as_float(u0 & 0xffff0000u);
        acc0[8+2*k]   += __uint_as_float(u1 << 16);
        acc0[8+2*k+1] += __uint_as_float(u1 & 0xffff0000u);
        acc1[2*k]   += __uint_as_float(u2 << 16);
        acc1[2*k+1] += __uint_as_float(u2 & 0xffff0000u);
        acc1[8+2*k]   += __uint_as_float(u3 << 16);
        acc1[8+2*k+1] += __uint_as_float(u3 & 0xffff0000u);
      }
      {
        float m0 = acc0[0], m1 = acc0[8];
#pragma unroll
        for (int k = 1; k < 8; ++k) { m0 = fmaxf(m0, acc0[k]); m1 = fmaxf(m1, acc0[8+k]); }
        m0 = fmaxf(m0, __shfl_xor(m0, 32, 64));
        m1 = fmaxf(m1, __shfl_xor(m1, 32, 64));
        float v = (hi ? m1 : m0) + biasv;
        out[(size_t)(g*4 + hi)*64 + fh*32 + (l & 31)] = fmaxf(v, 0.f);
      }
      {
        float m0 = acc1[0], m1 = acc1[8];
#pragma unroll
        for (int k = 1; k < 8; ++k) { m0 = fmaxf(m0, acc1[k]); m1 = fmaxf(m1, acc1[8+k]); }
        m0 = fmaxf(m0, __shfl_xor(m0, 32, 64));
        m1 = fmaxf(m1, __shfl_xor(m1, 32, 64));
        float v = (hi ? m1 : m0) + biasv;
        out[(size_t)(g*4 + 2 + hi)*64 + fh*32 + (l & 31)] = fmaxf(v, 0.f);
      }
    }

    // ---- Phase F: stage next group's patches (role split).
    // ch1 writes vertices 2,3 (offsets >= 2*VSTRIDE=7840 > 4KB xslots — no race with
    // ch0's xslot reads); ch0 writes vertices 0,1 after its own xslot reads (program order).
    if (vnext) {
#pragma unroll
      for (int it = 0; it < 12; ++it)
        *(uint2*)(pbase + (chv + (it & 1))*VSTRIDE + ((it >> 1)*8 + rsl)*ROWB + cp*8) = pack4(yv[it]);
      if (l < 16)
        *(uint2*)(pbase + (chv + rsl)*VSTRIDE + 48*ROWB + cp*8) = pack4(yc);
    }

    g = gn; valid = vnext;
  }
}

extern "C" void kernel_launch(void* const* d_in, const int* in_sizes, int n_in,
                              void* d_out, int out_size, void* d_ws, size_t ws_size,
                              hipStream_t stream) {
  const float* y     = (const float*)d_in[0];
  const int*   em    = (const int*)  d_in[1];
  const float* kern  = (const float*)d_in[2];
  const float* ckern = (const float*)d_in[3];
  const float* bias  = (const float*)d_in[4];
  float* out = (float*)d_out;
  unsigned short* bpack = (unsigned short*)d_ws;   // 200704 bytes used

  // opt in to >64KB dynamic LDS (host-side, graph-capture safe — verified rounds 1-7)
  hipFuncSetAttribute(reinterpret_cast<const void*>(conv_kernel),
                      hipFuncAttributeMaxDynamicSharedMemorySize, LDS_TOT);

  prepack_kernel<<<(2*BPACK_HALF_USHORT + 255)/256, 256, 0, stream>>>(kern, ckern, bpack);
  conv_kernel<<<256, 512, LDS_TOT, stream>>>(y, em, bias, bpack, out);
}

// Round 9
// 221.436 us; speedup vs baseline: 1.0938x; 1.0062x over previous
//
#include <hip/hip_runtime.h>
#include <hip/hip_bf16.h>
#include <stdint.h>

// Problem constants (B=2, NV=25000, C=32, NR=3, ND=16, F=64)
#define NVERT 25000      // vertices per batch
#define NPAIR 25000      // total vertex-pairs (B*NV/2)
#define NGRP  12500      // pair-groups of 2 pairs (4 vertices) per team-iter

typedef __bf16  bf16x8 __attribute__((ext_vector_type(8)));
typedef float   f32x16 __attribute__((ext_vector_type(16)));

#define NCHUNK 98                       // 96 conv chunks (r,ch,j) + 2 center chunks
#define BPACK_HALF_USHORT (NCHUNK*512)  // ushorts per f-half fragment pack
#define LDS_B   (NCHUNK*1024)           // 100352 B of B-fragments in LDS
#define ROWB    80                      // patch row stride (32 bf16 + 16B pad)
#define VSTRIDE (49*ROWB)               // per-vertex patch (48 rows + 1 center row) = 3920
#define WSTRIDE (4*VSTRIDE)             // per team: 4 vertices (2 pairs) = 15680
#define LDS_TOT (LDS_B + 4*WSTRIDE)     // 163072 <= 163840; one 512-thr block/CU = 2 waves/SIMD

__device__ __forceinline__ uint2 pack4(float4 v) {
  union { __hip_bfloat162 h; unsigned u; } a, b;
  a.h = __float22bfloat162_rn(float2{v.x, v.y});
  b.h = __float22bfloat162_rn(float2{v.z, v.w});
  return uint2{a.u, b.u};
}

__device__ __forceinline__ unsigned pk2(float a, float b) {
  union { __hip_bfloat162 h; unsigned u; } t;
  t.h = __float22bfloat162_rn(float2{a, b});
  return t.u;          // low16 = a, high16 = b
}

__device__ __forceinline__ unsigned short f2bf(float f) {
  unsigned int u = __float_as_uint(f);
  u += 0x7FFFu + ((u >> 16) & 1u);   // round-to-nearest-even
  return (unsigned short)(u >> 16);
}

// lane-rotate within 16-lane rows (row_ror:15): dst[i] = src[(i+1)&15] — verified (R1+ pass)
__device__ __forceinline__ bf16x8 rot16(bf16x8 x) {
  union { bf16x8 v; int i[4]; } u;
  u.v = x;
#pragma unroll
  for (int k = 0; k < 4; ++k)
    u.i[k] = __builtin_amdgcn_update_dpp(0, u.i[k], 0x12F, 0xF, 0xF, true);
  return u.v;
}

// Pack kernel (3,16,32,64) + center_kernel (32,64) into MFMA B-fragment order, bf16.
// Layout: bpack[fh(2)][kc(98)][lane(64)][i(8)] ushort.
// kc = (r*2+ch)*16 + j for conv; kc = 96+ch for center. B[k][n]: n=lane&31, k=8*(lane>>5)+i, c=ch*16+k.
__global__ __launch_bounds__(256) void prepack_kernel(
    const float* __restrict__ kern, const float* __restrict__ ckern,
    unsigned short* __restrict__ bpack)
{
  int tid = blockIdx.x*256 + threadIdx.x;
  if (tid >= 2*BPACK_HALF_USHORT) return;
  int fh  = tid / BPACK_HALF_USHORT;
  int rem = tid - fh*BPACK_HALF_USHORT;
  int kc  = rem >> 9;
  int e   = rem & 511;
  int l   = e >> 3, i = e & 7;
  int f   = fh*32 + (l & 31);
  int kk  = ((l >> 5) << 3) + i;
  float v;
  if (kc < 96) {
    int r = kc >> 5, ch = (kc >> 4) & 1, j = kc & 15;
    int c = ch*16 + kk;
    v = kern[((r*16 + j)*32 + c)*64 + f];
  } else {
    int c = (kc - 96)*16 + kk;
    v = ckern[c*64 + f];
  }
  bpack[tid] = f2bf(v);
}

// One r-pass for THIS wave's c-half: plain per-j B ds_read (imm offset; compiler
// software-pipelines with lgkmcnt(N) — m97 evidence). A rotated in-register (DPP).
#define PASS(rr)                                                               \
  {                                                                            \
    const char* ap = pbase + q*VSTRIDE + ((rr)*16 + d)*ROWB + choff + hi*16;   \
    bf16x8 a0 = *(const bf16x8*)ap;                                            \
    bf16x8 a1 = *(const bf16x8*)(ap + 2*VSTRIDE);                              \
    const char* bp = bbase + (size_t)(((rr)*2 + ch)*16) * 1024;                \
    _Pragma("unroll")                                                          \
    for (int j = 0; j < 16; ++j) {                                             \
      const bf16x8 b = *(const bf16x8*)(bp + (size_t)j*1024);                  \
      acc0 = __builtin_amdgcn_mfma_f32_32x32x16_bf16(a0, b, acc0, 0, 0, 0);    \
      acc1 = __builtin_amdgcn_mfma_f32_32x32x16_bf16(a1, b, acc1, 0, 0, 0);    \
      if (j < 15) { a0 = rot16(a0); a1 = rot16(a1); }                          \
    }                                                                          \
  }

__global__ __launch_bounds__(512, 2) void conv_kernel(
    const float* __restrict__ y,
    const int*   __restrict__ em,     // exp_map int pairs (b,v), flat (u*48 + r*16+dd)
    const float* __restrict__ bias,
    const unsigned short* __restrict__ bpack,
    float* __restrict__ out)
{
  extern __shared__ __align__(16) char smem[];
  const int fh  = blockIdx.x & 1;     // which 32-wide f half
  const int bl  = blockIdx.x >> 1;    // 0..127
  const int tid = threadIdx.x;
  const int w   = tid >> 6;           // wave 0..7
  const int tm  = w & 3;              // team 0..3 (patch region)
  const int ch  = w >> 2;             // role: c-half this wave computes
  const int l   = tid & 63;

  // ---- stage this f-half's B fragments into LDS (once per block) ----
  {
    const uint4* src = (const uint4*)(bpack + (size_t)fh * BPACK_HALF_USHORT);
    uint4* dst = (uint4*)smem;
    for (int idx = tid; idx < LDS_B/16; idx += 512) dst[idx] = src[idx];
  }
  // visibility ensured by B0 barrier at loop top (t=0)

  char* pbase = smem + LDS_B + tm * WSTRIDE;
  const char* bbase = smem + (size_t)l * 16;    // canonical fragment read: 0 conflicts (R3 PMC)
  const float biasv = bias[fh*32 + (l & 31)];
  const int gw = bl*4 + tm;           // team id within f-half, 0..511
  const int q  = (l >> 4) & 1;        // A-operand: which vertex of the pair (m>>4)
  const int d  = l & 15;              // A-operand: direction (m&15)
  const int hi = l >> 5;              // A/B operand: k-half selector
  const int choff = ch*32;            // byte offset of this wave's c-half within a row
  const int chv = ch*2;               // first vertex this role stages (role-split staging)
  const int rsl = l >> 3, cp = l & 7; // staging lane roles

  // staging base pointers (advance by imm-computable deltas; loads/stores use imm offsets)
  // em element index for it: (g*4 + chv + (it&1))*48 + (it>>1)*8 + rsl
  //   = [(g*4+chv)*48 + rsl] + (it&1)*48 + (it>>1)*8   -> byte offsets (it&1)*384 + (it>>1)*64
  // ds_write addr for it: [pbase + chv*VSTRIDE + rsl*ROWB + cp*8] + (it&1)*VSTRIDE + (it>>1)*8*ROWB
  char* const sbase = pbase + chv*VSTRIDE + rsl*ROWB + cp*8;

  int g = gw;
  bool valid = (g < NGRP);

  // ---- prologue: stage this role's half of group g (vertices chv, chv+1) ----
  if (valid) {
    const char* eb = (const char*)em + ((size_t)(g*4 + chv)*48 + rsl)*8;
    int2 e0[12];
#pragma unroll
    for (int it = 0; it < 12; ++it)
      e0[it] = *(const int2*)(eb + (it & 1)*384 + (it >> 1)*64);
    float4 yv0[12];
#pragma unroll
    for (int it = 0; it < 12; ++it) {
      const int rowi = e0[it].y + (e0[it].x ? NVERT : 0);   // e.x in {0,1}: cndmask, no mul
      yv0[it] = *(const float4*)(y + (size_t)rowi*32 + cp*4);
    }
    float4 yc0;
    if (l < 16) yc0 = *(const float4*)(y + (size_t)(g*4 + chv + rsl)*32 + cp*4);
#pragma unroll
    for (int it = 0; it < 12; ++it)
      *(uint2*)(sbase + (it & 1)*VSTRIDE + (it >> 1)*(8*ROWB)) = pack4(yv0[it]);
    if (l < 16)
      *(uint2*)(pbase + (chv + rsl)*VSTRIDE + 48*ROWB + cp*8) = pack4(yc0);
  }

  for (int t = 0; t < 25; ++t) {
    if (!valid) break;
    __syncthreads();   // B0: all staging (and t=0 B-pack copy) visible before reads

    const int gn = g + 512;
    const bool vnext = (gn < NGRP);

    // ---- Phase A: next group's em loads (one v-addr + imm offsets) ----
    int2 e[12];
    if (vnext) {
      const char* eb = (const char*)em + ((size_t)(gn*4 + chv)*48 + rsl)*8;
#pragma unroll
      for (int it = 0; it < 12; ++it)
        e[it] = *(const int2*)(eb + (it & 1)*384 + (it >> 1)*64);
    }

    f32x16 acc0, acc1;
#pragma unroll
    for (int k = 0; k < 16; ++k) { acc0[k] = 0.f; acc1[k] = 0.f; }

    // ---- Phase B: r=0 ----
    PASS(0)

    // ---- Phase C: next group's y gathers (latency hidden by r=1,2) ----
    float4 yv[12], yc;
    if (vnext) {
#pragma unroll
      for (int it = 0; it < 12; ++it) {
        const int rowi = e[it].y + (e[it].x ? NVERT : 0);
        yv[it] = *(const float4*)(y + (size_t)rowi*32 + cp*4);
      }
      if (l < 16) yc = *(const float4*)(y + (size_t)(gn*4 + chv + rsl)*32 + cp*4);
    }

    // ---- Phase D: r=1, r=2, center (this c-half only) ----
    PASS(1)
    PASS(2)
    {
      const bf16x8 bc = *(const bf16x8*)(bbase + (size_t)(96 + ch)*1024);
      const char* c0 = pbase + q*VSTRIDE + 48*ROWB + choff + hi*16;
      bf16x8 a0 = *(const bf16x8*)c0;
      bf16x8 a1 = *(const bf16x8*)(c0 + 2*VSTRIDE);
      acc0 = __builtin_amdgcn_mfma_f32_32x32x16_bf16(a0, bc, acc0, 0, 0, 0);
      acc1 = __builtin_amdgcn_mfma_f32_32x32x16_bf16(a1, bc, acc1, 0, 0, 0);
    }

    __syncthreads();   // B1: all patch A-reads of this group done

    // ---- Exchange: ch1 wave ships its partial accs (bf16-packed, 4KB) through
    //      the consumed patch region. Canonical layout: chunk*1024 + lane*16 (0 conflicts).
    if (ch) {
      uint4 s0 = {pk2(acc0[0],acc0[1]),  pk2(acc0[2],acc0[3]),
                  pk2(acc0[4],acc0[5]),  pk2(acc0[6],acc0[7])};
      uint4 s1 = {pk2(acc0[8],acc0[9]),  pk2(acc0[10],acc0[11]),
                  pk2(acc0[12],acc0[13]),pk2(acc0[14],acc0[15])};
      uint4 s2 = {pk2(acc1[0],acc1[1]),  pk2(acc1[2],acc1[3]),
                  pk2(acc1[4],acc1[5]),  pk2(acc1[6],acc1[7])};
      uint4 s3 = {pk2(acc1[8],acc1[9]),  pk2(acc1[10],acc1[11]),
                  pk2(acc1[12],acc1[13]),pk2(acc1[14],acc1[15])};
      *(uint4*)(pbase + 0*1024 + l*16) = s0;
      *(uint4*)(pbase + 1*1024 + l*16) = s1;
      *(uint4*)(pbase + 2*1024 + l*16) = s2;
      *(uint4*)(pbase + 3*1024 + l*16) = s3;
    }

    __syncthreads();   // B2: exchange visible

    if (!ch) {
      // ---- reduce + epilogue (ch0 wave): sum partner's c-half, max over d, +bias, relu ----
      // C/D layout (m74/m101): n = lane&31, m = (reg&3)+8*(reg>>2)+4*(lane>>5).
      uint4 x0 = *(const uint4*)(pbase + 0*1024 + l*16);
      uint4 x1 = *(const uint4*)(pbase + 1*1024 + l*16);
      uint4 x2 = *(const uint4*)(pbase + 2*1024 + l*16);
      uint4 x3 = *(const uint4*)(pbase + 3*1024 + l*16);
#pragma unroll
      for (int k = 0; k < 4; ++k) {
        unsigned u0 = (&x0.x)[k], u1 = (&x1.x)[k], u2 = (&x2.x)[k], u3 = (&x3.x)[k];
        acc0[2*k]   += __uint_as_float(u0 << 16);
        acc0[2*k+1] += __uint_as_float(u0 & 0xffff0000u);
        acc0[8+2*k]   += __uint_as_float(u1 << 16);
        acc0[8+2*k+1] += __uint_as_float(u1 & 0xffff0000u);
        acc1[2*k]   += __uint_as_float(u2 << 16);
        acc1[2*k+1] += __uint_as_float(u2 & 0xffff0000u);
        acc1[8+2*k]   += __uint_as_float(u3 << 16);
        acc1[8+2*k+1] += __uint_as_float(u3 & 0xffff0000u);
      }
      {
        float m0 = acc0[0], m1 = acc0[8];
#pragma unroll
        for (int k = 1; k < 8; ++k) { m0 = fmaxf(m0, acc0[k]); m1 = fmaxf(m1, acc0[8+k]); }
        m0 = fmaxf(m0, __shfl_xor(m0, 32, 64));
        m1 = fmaxf(m1, __shfl_xor(m1, 32, 64));
        float v = (hi ? m1 : m0) + biasv;
        out[(size_t)(g*4 + hi)*64 + fh*32 + (l & 31)] = fmaxf(v, 0.f);
      }
      {
        float m0 = acc1[0], m1 = acc1[8];
#pragma unroll
        for (int k = 1; k < 8; ++k) { m0 = fmaxf(m0, acc1[k]); m1 = fmaxf(m1, acc1[8+k]); }
        m0 = fmaxf(m0, __shfl_xor(m0, 32, 64));
        m1 = fmaxf(m1, __shfl_xor(m1, 32, 64));
        float v = (hi ? m1 : m0) + biasv;
        out[(size_t)(g*4 + 2 + hi)*64 + fh*32 + (l & 31)] = fmaxf(v, 0.f);
      }
    }

    // ---- Phase F: stage next group's patches (role split, imm-offset ds_writes).
    // ch1 writes vertices 2,3 (beyond the 4KB xslot); ch0 writes vertices 0,1 after
    // its xslot reads (program order within the wave).
    if (vnext) {
#pragma unroll
      for (int it = 0; it < 12; ++it)
        *(uint2*)(sbase + (it & 1)*VSTRIDE + (it >> 1)*(8*ROWB)) = pack4(yv[it]);
      if (l < 16)
        *(uint2*)(pbase + (chv + rsl)*VSTRIDE + 48*ROWB + cp*8) = pack4(yc);
    }

    g = gn; valid = vnext;
  }
}

extern "C" void kernel_launch(void* const* d_in, const int* in_sizes, int n_in,
                              void* d_out, int out_size, void* d_ws, size_t ws_size,
                              hipStream_t stream) {
  const float* y     = (const float*)d_in[0];
  const int*   em    = (const int*)  d_in[1];
  const float* kern  = (const float*)d_in[2];
  const float* ckern = (const float*)d_in[3];
  const float* bias  = (const float*)d_in[4];
  float* out = (float*)d_out;
  unsigned short* bpack = (unsigned short*)d_ws;   // 200704 bytes used

  // opt in to >64KB dynamic LDS (host-side, graph-capture safe — verified rounds 1-8)
  hipFuncSetAttribute(reinterpret_cast<const void*>(conv_kernel),
                      hipFuncAttributeMaxDynamicSharedMemorySize, LDS_TOT);

  prepack_kernel<<<(2*BPACK_HALF_USHORT + 255)/256, 256, 0, stream>>>(kern, ckern, bpack);
  conv_kernel<<<256, 512, LDS_TOT, stream>>>(y, em, bias, bpack, out);
}